// Round 1
// baseline (116.336 us; speedup 1.0000x reference)
//
#include <hip/hip_runtime.h>

// RankingLoss: B=16384 rows, D=512 f32, L=14 labels.
// Per row i (j=i+1 mod B):
//   paired  = dot(zi[i], zt[i])
//   imp_img = dot(zi[j], zt[i])
//   imp_txt = dot(zt[j], zi[i])
//   margin  = all-equal? 0 : max(0.5, xor_cnt / max(or_cnt,1))
//   loss   += relu(imp_img - paired + margin) + relu(imp_txt - paired + margin)
// out[0] = loss / B
//
// Memory-bound: 64 MiB unique input. One wave per 2 rows, float4 coalesced
// loads, shuffle reduce, per-block LDS combine, 2048 atomicAdds.

constexpr int B = 16384;
constexpr int D = 512;
constexpr int L = 14;
constexpr int BLOCK = 256;
constexpr int WAVES_PER_BLOCK = BLOCK / 64;      // 4
constexpr int ROWS_PER_WAVE = 2;
constexpr int GRID = B / (WAVES_PER_BLOCK * ROWS_PER_WAVE);  // 2048

__global__ __launch_bounds__(BLOCK) void rank_loss_kernel(
    const float* __restrict__ zi, const float* __restrict__ zt,
    const int* __restrict__ labels, float* __restrict__ out)
{
    const int lane = threadIdx.x & 63;
    const int wv   = threadIdx.x >> 6;
    const int gw   = blockIdx.x * WAVES_PER_BLOCK + wv;

    float acc = 0.0f;  // lane 0 of each wave accumulates its rows' loss

    #pragma unroll
    for (int r = 0; r < ROWS_PER_WAVE; ++r) {
        const int i = gw * ROWS_PER_WAVE + r;
        const int j = (i + 1) & (B - 1);

        const float4* zi_i = (const float4*)(zi + (size_t)i * D);
        const float4* zt_i = (const float4*)(zt + (size_t)i * D);
        const float4* zi_j = (const float4*)(zi + (size_t)j * D);
        const float4* zt_j = (const float4*)(zt + (size_t)j * D);

        // D/4 = 128 float4 per row; lane covers elements lane and lane+64.
        float pd = 0.0f, pii = 0.0f, pit = 0.0f;
        #pragma unroll
        for (int c = 0; c < 2; ++c) {
            const int idx = lane + 64 * c;
            const float4 a  = zi_i[idx];
            const float4 b  = zt_i[idx];
            const float4 aj = zi_j[idx];
            const float4 bj = zt_j[idx];
            pd  += a.x * b.x + a.y * b.y + a.z * b.z + a.w * b.w;
            pii += aj.x * b.x + aj.y * b.y + aj.z * b.z + aj.w * b.w;
            pit += bj.x * a.x + bj.y * a.y + bj.z * a.z + bj.w * a.w;
        }

        // Label stats packed into one int: or_cnt | xor_cnt<<8 | neq_cnt<<16
        // (each <= 14, fits in a byte).
        int pk = 0;
        if (lane < L) {
            const int a  = labels[i * L + lane];
            const int bv = labels[j * L + lane];
            pk = (a | bv) | ((a ^ bv) << 8) | ((int)(a != bv) << 16);
        }

        // Wave-wide reduction (width 64).
        #pragma unroll
        for (int off = 32; off > 0; off >>= 1) {
            pd  += __shfl_down(pd,  off);
            pii += __shfl_down(pii, off);
            pit += __shfl_down(pit, off);
            pk  += __shfl_down(pk,  off);
        }

        if (lane == 0) {
            const int n    = pk & 0xff;
            const int diff = (pk >> 8) & 0xff;
            const int neq  = (pk >> 16) & 0xff;
            float margin;
            if (neq == 0) {
                margin = 0.0f;
            } else {
                margin = fmaxf(0.5f, (float)diff / fmaxf((float)n, 1.0f));
            }
            acc += fmaxf(pii - pd + margin, 0.0f)
                 + fmaxf(pit - pd + margin, 0.0f);
        }
    }

    __shared__ float s[WAVES_PER_BLOCK];
    if (lane == 0) s[wv] = acc;
    __syncthreads();
    if (threadIdx.x == 0) {
        float t = 0.0f;
        #pragma unroll
        for (int w = 0; w < WAVES_PER_BLOCK; ++w) t += s[w];
        atomicAdd(out, t * (1.0f / (float)B));
    }
}

extern "C" void kernel_launch(void* const* d_in, const int* in_sizes, int n_in,
                              void* d_out, int out_size, void* d_ws, size_t ws_size,
                              hipStream_t stream) {
    const float* zi     = (const float*)d_in[0];
    const float* zt     = (const float*)d_in[1];
    const int*   labels = (const int*)d_in[2];
    float* out = (float*)d_out;

    // Harness poisons d_out with 0xAA before every timed launch.
    hipMemsetAsync(out, 0, sizeof(float), stream);
    rank_loss_kernel<<<GRID, BLOCK, 0, stream>>>(zi, zt, labels, out);
}

// Round 2
// 99.234 us; speedup vs baseline: 1.1723x; 1.1723x over previous
//
#include <hip/hip_runtime.h>

// RankingLoss: B=16384 rows, D=512 f32, L=14 labels.
// Per row i (j=i+1 mod B):
//   paired  = dot(zi[i], zt[i])
//   imp_img = dot(zi[j], zt[i])
//   imp_txt = dot(zt[j], zi[i])
//   margin  = all-equal? 0 : max(0.5, xor_cnt / or_cnt)
//   loss   += relu(imp_img - paired + margin) + relu(imp_txt - paired + margin)
// out[0] = loss / B
//
// v2: register-carry over row strips (each wave owns R=8 consecutive rows,
// reads R+1 rows once each -> ~144 MB logical vs 256 MB), label stats via
// __ballot/popcount, per-block partials to d_ws (NO same-address atomics,
// no memset), tiny reduce kernel writes the scalar.

constexpr int B = 16384;
constexpr int D = 512;        // 128 float4 per row
constexpr int L = 14;
constexpr int BLOCK = 256;
constexpr int WPB = BLOCK / 64;            // 4 waves per block
constexpr int R = 8;                        // rows per wave (register carry)
constexpr int GRID = B / (WPB * R);         // 512 blocks

__device__ __forceinline__ float dot4(float4 a, float4 b) {
    return a.x * b.x + a.y * b.y + a.z * b.z + a.w * b.w;
}

__global__ __launch_bounds__(BLOCK) void rank_main(
    const float* __restrict__ zi, const float* __restrict__ zt,
    const int* __restrict__ labels, float* __restrict__ ws)
{
    const int lane = threadIdx.x & 63;
    const int wv   = threadIdx.x >> 6;
    const int gw   = blockIdx.x * WPB + wv;
    const int base = gw * R;

    const float4* zi4 = (const float4*)zi;
    const float4* zt4 = (const float4*)zt;

    // Load row `base` of both matrices (2 float4 per lane per matrix).
    size_t o = (size_t)base * 128 + lane;
    float4 a0 = zi4[o], a1 = zi4[o + 64];
    float4 b0 = zt4[o], b1 = zt4[o + 64];
    int lab = (lane < L) ? labels[base * L + lane] : 0;
    float pd = dot4(a0, b0) + dot4(a1, b1);   // partial paired(base)

    float acc = 0.0f;   // lane 0: sum of hinge terms for this wave's rows

    #pragma unroll
    for (int r = 0; r < R; ++r) {
        const int nrow = (base + r + 1) & (B - 1);
        const size_t no = (size_t)nrow * 128 + lane;
        const float4 na0 = zi4[no], na1 = zi4[no + 64];
        const float4 nb0 = zt4[no], nb1 = zt4[no + 64];
        const int nlab = (lane < L) ? labels[nrow * L + lane] : 0;

        float pii = dot4(na0, b0) + dot4(na1, b1);   // dot(zi[j], zt[i])
        float pit = dot4(nb0, a0) + dot4(nb1, a1);   // dot(zt[j], zi[i])
        float npd = dot4(na0, nb0) + dot4(na1, nb1); // paired(next), reused

        // Label stats via ballot: lanes >= L contribute 0.
        const unsigned long long bor  = __ballot((lab | nlab) != 0);
        const unsigned long long bxor = __ballot((lab ^ nlab) != 0);

        // Reduce the three dot partials to lane 0.
        float s0 = pd, s1 = pii, s2 = pit;
        #pragma unroll
        for (int off = 32; off > 0; off >>= 1) {
            s0 += __shfl_down(s0, off);
            s1 += __shfl_down(s1, off);
            s2 += __shfl_down(s2, off);
        }

        if (lane == 0) {
            const int df = __popcll(bxor);
            float margin = 0.0f;
            if (df != 0) {
                const int n = __popcll(bor);   // n >= df >= 1
                margin = fmaxf(0.5f, (float)df / (float)n);
            }
            acc += fmaxf(s1 - s0 + margin, 0.0f)
                 + fmaxf(s2 - s0 + margin, 0.0f);
        }

        // Carry next row into current registers.
        a0 = na0; a1 = na1; b0 = nb0; b1 = nb1;
        lab = nlab; pd = npd;
    }

    __shared__ float s[WPB];
    if (lane == 0) s[wv] = acc;
    __syncthreads();
    if (threadIdx.x == 0)
        ws[blockIdx.x] = s[0] + s[1] + s[2] + s[3];
}

__global__ __launch_bounds__(BLOCK) void rank_reduce(
    const float* __restrict__ ws, float* __restrict__ out)
{
    // GRID (=512) partials; 256 threads, 2 each.
    float v = ws[threadIdx.x] + ws[threadIdx.x + BLOCK];
    #pragma unroll
    for (int off = 32; off > 0; off >>= 1) v += __shfl_down(v, off);
    __shared__ float s[WPB];
    if ((threadIdx.x & 63) == 0) s[threadIdx.x >> 6] = v;
    __syncthreads();
    if (threadIdx.x == 0)
        out[0] = (s[0] + s[1] + s[2] + s[3]) * (1.0f / (float)B);
}

extern "C" void kernel_launch(void* const* d_in, const int* in_sizes, int n_in,
                              void* d_out, int out_size, void* d_ws, size_t ws_size,
                              hipStream_t stream) {
    const float* zi     = (const float*)d_in[0];
    const float* zt     = (const float*)d_in[1];
    const int*   labels = (const int*)d_in[2];
    float* out = (float*)d_out;
    float* ws  = (float*)d_ws;

    rank_main<<<GRID, BLOCK, 0, stream>>>(zi, zt, labels, ws);
    rank_reduce<<<1, BLOCK, 0, stream>>>(ws, out);
}